// Round 4
// baseline (444.895 us; speedup 1.0000x reference)
//
#include <hip/hip_runtime.h>
#include <math.h>

#define B 1024
#define T 512
#define S 48
#define SOS 47

typedef float v2f __attribute__((ext_vector_type(2)));

// broadcast lane l's value to all lanes via the SGPR file (VALU op)
__device__ __forceinline__ float rdlanef(float v, int l) {
    return __int_as_float(__builtin_amdgcn_readlane(__float_as_int(v), l));
}

// REAL ds_bpermute broadcast: addr must come from a laundered (opaque) VGPR
// so LLVM cannot prove uniformity and fold this back to v_readlane (which is
// exactly what round 3 proved it does for constant addresses: identical
// VGPR/SGPR/dur/VALUBusy to the readlane version).
__device__ __forceinline__ float bpermf(int addr, float v) {
    return __int_as_float(__builtin_amdgcn_ds_bpermute(addr, __float_as_int(v)));
}

// ---------------------------------------------------------------------------
// Fused CRF loss. One wave per row; lane i owns state i; expT row in VGPRs.
// Scan kept in exp space with DELAYED normalization:
//   invariant  u_t = q * exp(M)   (exact; r_s == exp(-l_s) pending factor)
//   live step: q' = (expT q) * exp(emis - er) * r_s ;  M += er + l_s
//              then r_s = rcp(d1), l_s = log(d1)   [off critical chain]
//
// ROUND 4: with 1 wave/SIMD the wave's single issue port is the resource
// (~114 VALU ops x 2cyc ~= the measured 60% busy at ~1.2GHz effective clock).
// Two instruction-count levers, numerics bitwise identical to round 1:
//  (a) transport: 48 v_readlane -> 48 REAL ds_bpermute (addresses laundered
//      through asm "+v" so the uniform-fold can't fire). DS-pipe issue ~1cyc
//      vs VALU 2cyc, crossbar latency pipelines against the fma stream, and
//      the compiler still manages lgkmcnt (intrinsic, not inline-asm DS).
//      No write, no buffer (round-2 lesson): each bpermute depends only on q.
//  (b) math: 48 v_fma -> 24 v_pk_fma_f32 via float2 elementwise_fma.
//      Pairing (ax,ay)<-(j,j+1), (az,aw)<-(j+2,j+3) keeps each accumulator's
//      term sequence and the final (ax+ay)+(az+aw) EXACTLY round 1's.
// Emission/mask prefetch double-buffered per 8-step block (unchanged).
// amdgpu_waves_per_eu(1): full VGPR budget (structurally 1 wave/SIMD).
// ---------------------------------------------------------------------------
__global__ __launch_bounds__(64, 1)
__attribute__((amdgpu_waves_per_eu(1)))
void crf_fused(const float* __restrict__ feat,
               const int* __restrict__ states,
               const float* __restrict__ mask,
               const float* __restrict__ trans,
               float* __restrict__ out) {
    const int b = blockIdx.x;
    const int lane = threadIdx.x;
    const int elane = (lane < S) ? lane : 0;    // lanes 48-63 shadow lane 0
    const float* f_b = feat + (size_t)b * T * S;
    const float* m_b = mask + b * T;
    const int* st_b = states + b * T;

    // ---- numerator (latency overlaps expT setup) ----
    float nsum = 0.f;
#pragma unroll
    for (int k2 = 0; k2 < T / 64; ++k2) {
        const int t = lane + k2 * 64;
        const int st = st_b[t];
        const int pv = (t == 0) ? SOS : st_b[t - 1];
        nsum += (f_b[t * S + st] + trans[st * S + pv]) * m_b[t];
    }

    // ---- expT row for this lane, stored as float2 pairs for pk_fma;
    //      exp(-9999) underflows to exact 0 ----
    v2f expTp[S / 2];
    {
        const float4* t4 = (const float4*)(trans + elane * S);
#pragma unroll
        for (int j4 = 0; j4 < S / 4; ++j4) {
            const float4 tv = t4[j4];
            expTp[2 * j4 + 0].x = (lane < S) ? __expf(tv.x) : 0.f;
            expTp[2 * j4 + 0].y = (lane < S) ? __expf(tv.y) : 0.f;
            expTp[2 * j4 + 1].x = (lane < S) ? __expf(tv.z) : 0.f;
            expTp[2 * j4 + 1].y = (lane < S) ? __expf(tv.w) : 0.f;
        }
    }

    // ---- laundered broadcast addresses: opaque VGPRs -> real ds_bpermute ----
    int baddr[S];
#pragma unroll
    for (int j = 0; j < S; ++j) {
        int a = 4 * j;
        asm("" : "+v"(a));          // defeat uniform-index fold
        baddr[j] = a;
    }

    // ---- scan state ----
    float q = (lane == SOS) ? 1.f : 0.f;        // lanes >= 48 hold 0 forever
    float M = 0.f;
    float r_s = 1.f, l_s = 0.f;      // pending normalizer: r_s == exp(-l_s)

    // emission/mask double-buffered block rings (8 steps per block)
    float ering[2][8], mring[2][8];
#pragma unroll
    for (int k = 0; k < 8; ++k) {
        ering[0][k] = f_b[k * S + elane];
        mring[0][k] = m_b[k];
    }

#pragma unroll 2
    for (int tb = 0; tb < T / 8; ++tb) {
        const int pb = tb & 1;
        // issue next block's loads now; consumed a full block later
        const int tn = ((tb + 1) & (T / 8 - 1)) * 8;   // wrap: last refill unused
#pragma unroll
        for (int k = 0; k < 8; ++k) {
            ering[pb ^ 1][k] = f_b[(tn + k) * S + elane];
            mring[pb ^ 1][k] = m_b[tn + k];
        }
#pragma unroll
        for (int k = 0; k < 8; ++k) {
            // off-chain: per-lane factor from prefetched emission
            const float emis = ering[pb][k];
            const float er = rdlanef(emis, 1);
            const float F = __expf(emis - er) * r_s;
            // chain: DS-crossbar-broadcast dot d_i = expT[i] . q
            //   48 ds_bpermute (DS pipe, mutually independent, no write)
            //   24 v_pk_fma_f32 (VALU), bitwise round-1 accumulation order
            v2f accA = {0.f, 0.f}, accB = {0.f, 0.f};
#pragma unroll
            for (int j4 = 0; j4 < S / 4; ++j4) {
                v2f qA, qB;
                qA.x = bpermf(baddr[4 * j4 + 0], q);
                qA.y = bpermf(baddr[4 * j4 + 1], q);
                qB.x = bpermf(baddr[4 * j4 + 2], q);
                qB.y = bpermf(baddr[4 * j4 + 3], q);
                accA = __builtin_elementwise_fma(expTp[2 * j4 + 0], qA, accA);
                accB = __builtin_elementwise_fma(expTp[2 * j4 + 1], qB, accB);
            }
            const float d = (accA.x + accA.y) + (accB.x + accB.y);
            const float qn = d * F;
            const bool live = (mring[pb][k] != 0.f);
            q = live ? qn : q;                  // SELECT, never blend
            // off-chain: next normalizer + shift bookkeeping
            M = live ? (M + er + l_s) : M;      // uses OLD l_s, then update
            const float dr = rdlanef(d, 1);     // lane1 dot: provably > 0
            const float nl = __logf(dr);
            const float nr = __builtin_amdgcn_rcpf(dr);
            r_s = live ? nr : r_s;
            l_s = live ? nl : l_s;
        }
    }

    // ---- epilogue: denom = M + log(sum_i q_i); out = denom - numer ----
    float ps = q;                               // lanes >= 48 hold 0
#pragma unroll
    for (int off = 32; off > 0; off >>= 1) {
        ps += __shfl_xor(ps, off, 64);
        nsum += __shfl_xor(nsum, off, 64);
    }
    if (lane == 0) out[b] = M + __logf(ps) - nsum;
}

extern "C" void kernel_launch(void* const* d_in, const int* in_sizes, int n_in,
                              void* d_out, int out_size, void* d_ws, size_t ws_size,
                              hipStream_t stream) {
    const float* feat   = (const float*)d_in[0];   // (B,T,S) f32
    const int*   states = (const int*)d_in[1];     // (B,T) i32
    const float* mask   = (const float*)d_in[2];   // (B,T) f32
    const float* trans  = (const float*)d_in[3];   // (S,S) f32
    float* out = (float*)d_out;                    // (B,) f32

    crf_fused<<<dim3(B), dim3(64), 0, stream>>>(feat, states, mask, trans, out);
}

// Round 6
// 254.109 us; speedup vs baseline: 1.7508x; 1.7508x over previous
//
#include <hip/hip_runtime.h>
#include <math.h>

#define B 1024
#define T 512
#define S 48
#define SOS 47

typedef float v2f __attribute__((ext_vector_type(2)));

// broadcast lane l's value to all lanes via the SGPR file (VALU op)
__device__ __forceinline__ float rdlanef(float v, int l) {
    return __int_as_float(__builtin_amdgcn_readlane(__float_as_int(v), l));
}

// ---------------------------------------------------------------------------
// Fused CRF loss. One wave per row; lane i owns state i; expT row in VGPRs.
// Scan kept in exp space with DELAYED normalization:
//   invariant  u_t = q * exp(M)   (exact; r_s == exp(-l_s) pending factor)
//   live step: q' = (expT q) * exp(emis - er) * r_s ;  M += er + l_s
//              then r_s = rcp(d1), l_s = log(d1)   [off critical chain]
//
// ROUND 6 == ROUND 5 RESUBMITTED (round-5 bench died on container
// acquisition, no kernel verdict). Two-line hardening: early-clobber on the
// seed asm blocks. Design rationale unchanged:
//
// Keep round-1 transport (v_readlane -> SGPR: rounds 2/3/4 proved every
// DS-pipe alternative loses -- bpermute was 2.4x WORSE, 15% VALUBusy),
// halve the FMA stream with full-rate packed fp32:
//   MI355X fp32 peak 157.3TF = 256CU x 64lane x 2FLOP x 2(PACKED) x 2.4GHz,
//   i.e. v_pk_fma_f32 does 2 FMAs per 2-cyc issue slot.
// Naive float2 codegen would insert 2x v_mov (s->v) per pair because VOP3P
// needs a 64-bit source -- cancelling the win. Instead each j-pair is one
// 3-instr asm unit: 2x v_readlane into the HARD ALIGNED pair s[20:21], then
//   v_pk_fma_f32 acc, expT_pair, s[20:21], acc
// (VOP3P may read one 64-bit SGPR-pair source = one scalar-operand read).
// Blocks are self-contained (s20/21 written then read inside the same unit),
// so the scheduler freely interleaves the independent accA/accB chains +
// off-chain bookkeeping. First pair per accumulator is v_pk_mul_f32
// (bitwise == fma into 0.0). Pairing accA=(ax,ay), accB=(az,aw); per-chain
// term order and the final (ax+ay)+(az+aw) BITWISE IDENTICAL to round 1.
// Per-step issue: 48rl + 24pk + bookkeeping ~= 150-190 cyc vs ~222 before.
// Emission/mask prefetch double-buffered per 8-step block (unchanged).
// amdgpu_waves_per_eu(1): full VGPR budget (structurally 1 wave/SIMD).
// ---------------------------------------------------------------------------
__global__ __launch_bounds__(64, 1)
__attribute__((amdgpu_waves_per_eu(1)))
void crf_fused(const float* __restrict__ feat,
               const int* __restrict__ states,
               const float* __restrict__ mask,
               const float* __restrict__ trans,
               float* __restrict__ out) {
    const int b = blockIdx.x;
    const int lane = threadIdx.x;
    const int elane = (lane < S) ? lane : 0;    // lanes 48-63 shadow lane 0
    const float* f_b = feat + (size_t)b * T * S;
    const float* m_b = mask + b * T;
    const int* st_b = states + b * T;

    // ---- numerator (latency overlaps expT setup) ----
    float nsum = 0.f;
#pragma unroll
    for (int k2 = 0; k2 < T / 64; ++k2) {
        const int t = lane + k2 * 64;
        const int st = st_b[t];
        const int pv = (t == 0) ? SOS : st_b[t - 1];
        nsum += (f_b[t * S + st] + trans[st * S + pv]) * m_b[t];
    }

    // ---- expT row for this lane, stored as aligned float2 pairs for
    //      v_pk_fma_f32; exp(-9999) underflows to exact 0 ----
    v2f expTp[S / 2];
    {
        const float4* t4 = (const float4*)(trans + elane * S);
#pragma unroll
        for (int j4 = 0; j4 < S / 4; ++j4) {
            const float4 tv = t4[j4];
            expTp[2 * j4 + 0].x = (lane < S) ? __expf(tv.x) : 0.f;
            expTp[2 * j4 + 0].y = (lane < S) ? __expf(tv.y) : 0.f;
            expTp[2 * j4 + 1].x = (lane < S) ? __expf(tv.z) : 0.f;
            expTp[2 * j4 + 1].y = (lane < S) ? __expf(tv.w) : 0.f;
        }
    }

    // ---- scan state ----
    float q = (lane == SOS) ? 1.f : 0.f;        // lanes >= 48 hold 0 forever
    float M = 0.f;
    float r_s = 1.f, l_s = 0.f;      // pending normalizer: r_s == exp(-l_s)

    // emission/mask double-buffered block rings (8 steps per block)
    float ering[2][8], mring[2][8];
#pragma unroll
    for (int k = 0; k < 8; ++k) {
        ering[0][k] = f_b[k * S + elane];
        mring[0][k] = m_b[k];
    }

#pragma unroll 2
    for (int tb = 0; tb < T / 8; ++tb) {
        const int pb = tb & 1;
        // issue next block's loads now; consumed a full block later
        const int tn = ((tb + 1) & (T / 8 - 1)) * 8;   // wrap: last refill unused
#pragma unroll
        for (int k = 0; k < 8; ++k) {
            ering[pb ^ 1][k] = f_b[(tn + k) * S + elane];
            mring[pb ^ 1][k] = m_b[tn + k];
        }
#pragma unroll
        for (int k = 0; k < 8; ++k) {
            // off-chain: per-lane factor from prefetched emission
            const float emis = ering[pb][k];
            const float er = rdlanef(emis, 1);
            const float F = __expf(emis - er) * r_s;
            // chain: dot d_i = expT[i] . q
            //   48 v_readlane (2 per unit, into aligned s[20:21]) feeding
            //   24 v_pk_fma_f32 (first per chain: v_pk_mul == fma into 0)
            v2f accA, accB;
            asm("v_readlane_b32 s20, %1, 0\n\t"
                "v_readlane_b32 s21, %1, 1\n\t"
                "v_pk_mul_f32 %0, %2, s[20:21]"
                : "=&v"(accA) : "v"(q), "v"(expTp[0]) : "s20", "s21");
            asm("v_readlane_b32 s20, %1, 2\n\t"
                "v_readlane_b32 s21, %1, 3\n\t"
                "v_pk_mul_f32 %0, %2, s[20:21]"
                : "=&v"(accB) : "v"(q), "v"(expTp[1]) : "s20", "s21");
#pragma unroll
            for (int j4 = 1; j4 < S / 4; ++j4) {
                asm("v_readlane_b32 s20, %1, %2\n\t"
                    "v_readlane_b32 s21, %1, %3\n\t"
                    "v_pk_fma_f32 %0, %4, s[20:21], %0"
                    : "+v"(accA)
                    : "v"(q), "i"(4 * j4 + 0), "i"(4 * j4 + 1),
                      "v"(expTp[2 * j4 + 0])
                    : "s20", "s21");
                asm("v_readlane_b32 s20, %1, %2\n\t"
                    "v_readlane_b32 s21, %1, %3\n\t"
                    "v_pk_fma_f32 %0, %4, s[20:21], %0"
                    : "+v"(accB)
                    : "v"(q), "i"(4 * j4 + 2), "i"(4 * j4 + 3),
                      "v"(expTp[2 * j4 + 1])
                    : "s20", "s21");
            }
            const float d = (accA.x + accA.y) + (accB.x + accB.y);
            const float qn = d * F;
            const bool live = (mring[pb][k] != 0.f);
            q = live ? qn : q;                  // SELECT, never blend
            // off-chain: next normalizer + shift bookkeeping
            M = live ? (M + er + l_s) : M;      // uses OLD l_s, then update
            const float dr = rdlanef(d, 1);     // lane1 dot: provably > 0
            const float nl = __logf(dr);
            const float nr = __builtin_amdgcn_rcpf(dr);
            r_s = live ? nr : r_s;
            l_s = live ? nl : l_s;
        }
    }

    // ---- epilogue: denom = M + log(sum_i q_i); out = denom - numer ----
    float ps = q;                               // lanes >= 48 hold 0
#pragma unroll
    for (int off = 32; off > 0; off >>= 1) {
        ps += __shfl_xor(ps, off, 64);
        nsum += __shfl_xor(nsum, off, 64);
    }
    if (lane == 0) out[b] = M + __logf(ps) - nsum;
}

extern "C" void kernel_launch(void* const* d_in, const int* in_sizes, int n_in,
                              void* d_out, int out_size, void* d_ws, size_t ws_size,
                              hipStream_t stream) {
    const float* feat   = (const float*)d_in[0];   // (B,T,S) f32
    const int*   states = (const int*)d_in[1];     // (B,T) i32
    const float* mask   = (const float*)d_in[2];   // (B,T) f32
    const float* trans  = (const float*)d_in[3];   // (S,S) f32
    float* out = (float*)d_out;                    // (B,) f32

    crf_fused<<<dim3(B), dim3(64), 0, stream>>>(feat, states, mask, trans, out);
}